// Round 2
// baseline (367.995 us; speedup 1.0000x reference)
//
#include <hip/hip_runtime.h>

#define NEG_INF (-3.402823466e+38f)
#define SCALE 0.17677669529663689f  // 1/sqrt(32)

typedef __attribute__((ext_vector_type(8))) short bf16x8;
typedef __attribute__((ext_vector_type(4))) float f32x4;
typedef __attribute__((ext_vector_type(4))) unsigned short u16x4;

__device__ __forceinline__ unsigned short f2bf(float f) {
  union { float f; unsigned u; } v; v.f = f;
  unsigned r = v.u + 0x7fffu + ((v.u >> 16) & 1u);
  return (unsigned short)(r >> 16);
}
__device__ __forceinline__ float bf2f(unsigned short h) {
  union { unsigned u; float f; } v; v.u = ((unsigned)h) << 16; return v.f;
}

__device__ __forceinline__ bf16x8 pack_bf8(const float* __restrict__ p) {
  float4 a = *(const float4*)p;
  float4 b = *(const float4*)(p + 4);
  bf16x8 r;
  r[0] = (short)f2bf(a.x); r[1] = (short)f2bf(a.y);
  r[2] = (short)f2bf(a.z); r[3] = (short)f2bf(a.w);
  r[4] = (short)f2bf(b.x); r[5] = (short)f2bf(b.y);
  r[6] = (short)f2bf(b.z); r[7] = (short)f2bf(b.w);
  return r;
}

// Weights -> bf16. wk additionally transposed: wkT[i][o] = wk[o][i].
__global__ __launch_bounds__(256) void cvt_weights(
    const float* __restrict__ wq, const float* __restrict__ wk,
    const float* __restrict__ wv, const float* __restrict__ wo,
    unsigned short* __restrict__ oq, unsigned short* __restrict__ okT,
    unsigned short* __restrict__ ov, unsigned short* __restrict__ oo) {
  int i = blockIdx.x * 256 + threadIdx.x;
  if (i < 128 * 128) {
    oq[i] = f2bf(wq[i]);
    ov[i] = f2bf(wv[i]);
    oo[i] = f2bf(wo[i]);
    int o = i >> 7, ii = i & 127;
    okT[ii * 128 + o] = f2bf(wk[i]);
  }
}

// Y[M][128] = X[M][128] @ W^T, W bf16 [o][i]. 256 thr = 4 waves, 64 rows/block.
__global__ __launch_bounds__(256) void gemm_xwt(
    const float* __restrict__ X, const unsigned short* __restrict__ Wbf,
    float* __restrict__ Y, int M) {
  __shared__ unsigned short Wl[128 * 136];
  for (int idx = threadIdx.x; idx < 128 * 128; idx += 256)
    Wl[(idx >> 7) * 136 + (idx & 127)] = Wbf[idx];
  __syncthreads();

  const int wave = threadIdx.x >> 6, lane = threadIdx.x & 63;
  const int lr = lane & 15, lk = lane >> 4;
  const int row0 = blockIdx.x * 64 + wave * 16;
  const int arow = row0 + lr;

  bf16x8 af[4];
  if (arow < M) {
    const float* xr = X + (size_t)arow * 128;
#pragma unroll
    for (int kk = 0; kk < 4; ++kk) af[kk] = pack_bf8(xr + kk * 32 + lk * 8);
  } else {
#pragma unroll
    for (int kk = 0; kk < 4; ++kk) af[kk] = (bf16x8)(short)0;
  }

  f32x4 acc[8];
#pragma unroll
  for (int ct = 0; ct < 8; ++ct) acc[ct] = (f32x4){0.f, 0.f, 0.f, 0.f};

#pragma unroll
  for (int kk = 0; kk < 4; ++kk) {
#pragma unroll
    for (int ct = 0; ct < 8; ++ct) {
      bf16x8 b = *(const bf16x8*)&Wl[(ct * 16 + lr) * 136 + kk * 32 + lk * 8];
      acc[ct] = __builtin_amdgcn_mfma_f32_16x16x32_bf16(af[kk], b, acc[ct], 0, 0, 0);
    }
  }

#pragma unroll
  for (int ct = 0; ct < 8; ++ct) {
#pragma unroll
    for (int r = 0; r < 4; ++r) {
      int row = row0 + lk * 4 + r;
      if (row < M) Y[(size_t)row * 128 + ct * 16 + lr] = acc[ct][r];
    }
  }
}

// Fused neighbor attention, v2. 192 threads = 3 waves; one node per wave per
// iter, 2 iters => 6 nodes/block. Weights read from global (L1/L2-resident).
// K never materialized: logits via WQ = Qdiag@Wk (MFMA) then E@WQ^T (MFMA).
__global__ __launch_bounds__(192, 4) void neigh_attn2(
    const float* __restrict__ hE, const int* __restrict__ mask,
    const unsigned short* __restrict__ wkT, const unsigned short* __restrict__ wv,
    const float* __restrict__ Qg, float* __restrict__ attOut, int N) {
  __shared__ unsigned short vT[3][128 * 36];   // V col-major [o][k], pitch 36
  __shared__ unsigned short wqs[3][4 * 136];   // WQ [h][i] bf16, pitch 136
  __shared__ float attL[3][128];               // att [h][k] f32

  const int wave = threadIdx.x >> 6, lane = threadIdx.x & 63;
  const int lr = lane & 15, lk = lane >> 4;
  unsigned short* vTw = vT[wave];
  unsigned short* wqw = wqs[wave];
  float* attw = attL[wave];

  for (int it = 0; it < 2; ++it) {
    const int n = blockIdx.x * 6 + wave * 2 + it;
    if (n >= N) break;
    const float* E = hE + (size_t)n * 4096;

    // A-fragments of the 32x128 E tile (row = lr, k-chunk = lk*8)
    bf16x8 af[2][4];
#pragma unroll
    for (int rt = 0; rt < 2; ++rt)
#pragma unroll
      for (int kk = 0; kk < 4; ++kk)
        af[rt][kk] = pack_bf8(E + (rt * 16 + lr) * 128 + kk * 32 + lk * 8);

    // Q segment for the block-diagonal A of MFMA1 (head lr, lanes lr<4 used)
    bf16x8 qf = pack_bf8(Qg + (size_t)n * 128 + (lr & 3) * 32 + lk * 8);

    // ---- MFMA1: WQ[h][i] = sum_d Qdiag[h][d] * Wk[d][i]  (B = wkT, i-major)
#pragma unroll
    for (int ct = 0; ct < 8; ++ct) {
      f32x4 c = (f32x4){0.f, 0.f, 0.f, 0.f};
#pragma unroll
      for (int kk = 0; kk < 4; ++kk) {
        bf16x8 a = (lr == kk) ? qf : (bf16x8)(short)0;
        bf16x8 b = *(const bf16x8*)(wkT + (ct * 16 + lr) * 128 + kk * 32 + lk * 8);
        c = __builtin_amdgcn_mfma_f32_16x16x32_bf16(a, b, c, 0, 0, 0);
      }
      if (lk == 0) {  // rows 0..3 live on lk==0 lanes: WQ[h=r][i=ct*16+lr]
#pragma unroll
        for (int r = 0; r < 4; ++r) wqw[r * 136 + ct * 16 + lr] = f2bf(c[r]);
      }
    }

    // ---- MFMA2: logits[k][h] = E @ WQ^T   (B row lr&3 = head, cols>=4 junk)
    f32x4 c2[2];
    c2[0] = (f32x4){0.f, 0.f, 0.f, 0.f};
    c2[1] = (f32x4){0.f, 0.f, 0.f, 0.f};
#pragma unroll
    for (int kk = 0; kk < 4; ++kk) {
      bf16x8 b = *(const bf16x8*)&wqw[(lr & 3) * 136 + kk * 32 + lk * 8];
      c2[0] = __builtin_amdgcn_mfma_f32_16x16x32_bf16(af[0][kk], b, c2[0], 0, 0, 0);
      c2[1] = __builtin_amdgcn_mfma_f32_16x16x32_bf16(af[1][kk], b, c2[1], 0, 0, 0);
    }

    // ---- masked softmax fully in-register. lane holds k = rt*16+lk*4+r, h=lr
    const int4 m0 = *(const int4*)(mask + (size_t)n * 32 + lk * 4);
    const int4 m1 = *(const int4*)(mask + (size_t)n * 32 + 16 + lk * 4);
    float l[2][4];
    l[0][0] = m0.x ? c2[0][0] * SCALE : NEG_INF;
    l[0][1] = m0.y ? c2[0][1] * SCALE : NEG_INF;
    l[0][2] = m0.z ? c2[0][2] * SCALE : NEG_INF;
    l[0][3] = m0.w ? c2[0][3] * SCALE : NEG_INF;
    l[1][0] = m1.x ? c2[1][0] * SCALE : NEG_INF;
    l[1][1] = m1.y ? c2[1][1] * SCALE : NEG_INF;
    l[1][2] = m1.z ? c2[1][2] * SCALE : NEG_INF;
    l[1][3] = m1.w ? c2[1][3] * SCALE : NEG_INF;

    float mx = l[0][0];
#pragma unroll
    for (int rt = 0; rt < 2; ++rt)
#pragma unroll
      for (int r = 0; r < 4; ++r) mx = fmaxf(mx, l[rt][r]);
    mx = fmaxf(mx, __shfl_xor(mx, 16, 64));
    mx = fmaxf(mx, __shfl_xor(mx, 32, 64));

    float e[2][4];
    float sum = 0.f;
#pragma unroll
    for (int rt = 0; rt < 2; ++rt)
#pragma unroll
      for (int r = 0; r < 4; ++r) { e[rt][r] = __expf(l[rt][r] - mx); sum += e[rt][r]; }
    sum += __shfl_xor(sum, 16, 64);
    sum += __shfl_xor(sum, 32, 64);
    const float inv = 1.0f / sum;

    if (lr < 4) {
      float4 a0 = make_float4(m0.x ? e[0][0] * inv : 0.f, m0.y ? e[0][1] * inv : 0.f,
                              m0.z ? e[0][2] * inv : 0.f, m0.w ? e[0][3] * inv : 0.f);
      float4 a1 = make_float4(m1.x ? e[1][0] * inv : 0.f, m1.y ? e[1][1] * inv : 0.f,
                              m1.z ? e[1][2] * inv : 0.f, m1.w ? e[1][3] * inv : 0.f);
      *(float4*)&attw[lr * 32 + lk * 4] = a0;
      *(float4*)&attw[lr * 32 + 16 + lk * 4] = a1;
    }

    // ---- V projection, streamed per ct, written col-major vT[o][k]
#pragma unroll
    for (int ct = 0; ct < 8; ++ct) {
      f32x4 cv0 = (f32x4){0.f, 0.f, 0.f, 0.f};
      f32x4 cv1 = (f32x4){0.f, 0.f, 0.f, 0.f};
#pragma unroll
      for (int kk = 0; kk < 4; ++kk) {
        bf16x8 b = *(const bf16x8*)(wv + (ct * 16 + lr) * 128 + kk * 32 + lk * 8);
        cv0 = __builtin_amdgcn_mfma_f32_16x16x32_bf16(af[0][kk], b, cv0, 0, 0, 0);
        cv1 = __builtin_amdgcn_mfma_f32_16x16x32_bf16(af[1][kk], b, cv1, 0, 0, 0);
      }
      // lane holds V[k=rt*16+lk*4+r][o=ct*16+lr] -> b64 packed along r
      u16x4 p0, p1;
#pragma unroll
      for (int r = 0; r < 4; ++r) { p0[r] = f2bf(cv0[r]); p1[r] = f2bf(cv1[r]); }
      *(u16x4*)&vTw[(ct * 16 + lr) * 36 + lk * 4] = p0;
      *(u16x4*)&vTw[(ct * 16 + lr) * 36 + 16 + lk * 4] = p1;
    }

    // ---- PV: out[o] = sum_k att[h][k] * V[k][o]
#pragma unroll
    for (int half = 0; half < 2; ++half) {
      const int o = lane + 64 * half;
      const int h = o >> 5;
      const float* ar = attw + h * 32;
      const unsigned short* vr = vTw + o * 36;
      float acc = 0.f;
#pragma unroll
      for (int kc = 0; kc < 8; ++kc) {
        u16x4 vv = *(const u16x4*)&vr[kc * 4];
        float4 aa = *(const float4*)&ar[kc * 4];
        acc += aa.x * bf2f(vv[0]) + aa.y * bf2f(vv[1]) +
               aa.z * bf2f(vv[2]) + aa.w * bf2f(vv[3]);
      }
      attOut[(size_t)n * 128 + o] = acc;
    }
  }
}

extern "C" void kernel_launch(void* const* d_in, const int* in_sizes, int n_in,
                              void* d_out, int out_size, void* d_ws, size_t ws_size,
                              hipStream_t stream) {
  const float* hV = (const float*)d_in[0];
  const float* hE = (const float*)d_in[1];
  const int* mask = (const int*)d_in[2];
  const float* Wq = (const float*)d_in[3];
  const float* Wk = (const float*)d_in[4];
  const float* Wv = (const float*)d_in[5];
  const float* Wo = (const float*)d_in[6];
  float* out = (float*)d_out;
  const int N = in_sizes[0] / 128;  // 30000

  char* ws = (char*)d_ws;
  unsigned short* wqb = (unsigned short*)(ws);
  unsigned short* wkTb = (unsigned short*)(ws + 32768);
  unsigned short* wvb = (unsigned short*)(ws + 65536);
  unsigned short* wob = (unsigned short*)(ws + 98304);
  float* Qbuf = (float*)(ws + 131072);
  float* Abuf = (float*)(ws + 131072 + (size_t)N * 128 * 4);

  cvt_weights<<<64, 256, 0, stream>>>(Wq, Wk, Wv, Wo, wqb, wkTb, wvb, wob);
  gemm_xwt<<<(N + 63) / 64, 256, 0, stream>>>(hV, wqb, Qbuf, N);
  neigh_attn2<<<(N + 5) / 6, 192, 0, stream>>>(hE, mask, wkTb, wvb, Qbuf, Abuf, N);
  gemm_xwt<<<(N + 63) / 64, 256, 0, stream>>>(Abuf, wob, out, N);
}

// Round 3
// 166.064 us; speedup vs baseline: 2.2160x; 2.2160x over previous
//
#include <hip/hip_runtime.h>

#define NEG_INF (-3.402823466e+38f)
#define SCALE 0.17677669529663689f  // 1/sqrt(32)

typedef __attribute__((ext_vector_type(8))) short bf16x8;
typedef __attribute__((ext_vector_type(4))) float f32x4;
typedef __attribute__((ext_vector_type(4))) unsigned short u16x4;

__device__ __forceinline__ unsigned short f2bf(float f) {
  union { float f; unsigned u; } v; v.f = f;
  unsigned r = v.u + 0x7fffu + ((v.u >> 16) & 1u);
  return (unsigned short)(r >> 16);
}
__device__ __forceinline__ float bf2f(unsigned short h) {
  union { unsigned u; float f; } v; v.u = ((unsigned)h) << 16; return v.f;
}

__device__ __forceinline__ bf16x8 pack_bf8(const float* __restrict__ p) {
  float4 a = *(const float4*)p;
  float4 b = *(const float4*)(p + 4);
  bf16x8 r;
  r[0] = (short)f2bf(a.x); r[1] = (short)f2bf(a.y);
  r[2] = (short)f2bf(a.z); r[3] = (short)f2bf(a.w);
  r[4] = (short)f2bf(b.x); r[5] = (short)f2bf(b.y);
  r[6] = (short)f2bf(b.z); r[7] = (short)f2bf(b.w);
  return r;
}

// Precompute fused weight products (bf16):
//  MT[h][i][j] = M_h[j][i] = sum_d Wq[h*32+d][j] * Wk[h*32+d][i]
//  WB[o][h*128+i]          = sum_d Wo[o][h*32+d] * Wv[h*32+d][i]
// One wave per 16x16 tile; 256 tiles total.
__global__ __launch_bounds__(256) void fuse_weights(
    const float* __restrict__ wq, const float* __restrict__ wk,
    const float* __restrict__ wv, const float* __restrict__ wo,
    unsigned short* __restrict__ MT, unsigned short* __restrict__ WB) {
  const int w = (blockIdx.x * 256 + threadIdx.x) >> 6;  // wave id 0..255
  const int lane = threadIdx.x & 63;
  const int lr = lane & 15, lk = lane >> 4;
  const int h = w >> 6, t2 = w & 63, jt = t2 >> 3, it = t2 & 7;

  // ---- M tile: D[j_local][i_local], K = 32 (the d dimension) ----
  bf16x8 a, b;
#pragma unroll
  for (int j = 0; j < 8; ++j) {
    a[j] = (short)f2bf(wq[(h * 32 + lk * 8 + j) * 128 + jt * 16 + lr]);
    b[j] = (short)f2bf(wk[(h * 32 + lk * 8 + j) * 128 + it * 16 + lr]);
  }
  f32x4 c = (f32x4){0.f, 0.f, 0.f, 0.f};
  c = __builtin_amdgcn_mfma_f32_16x16x32_bf16(a, b, c, 0, 0, 0);
#pragma unroll
  for (int r = 0; r < 4; ++r)
    MT[h * 16384 + (it * 16 + lr) * 128 + jt * 16 + lk * 4 + r] = f2bf(c[r]);

  // ---- WB tile: D[o_local][i_local], ot = jt ----
  bf16x8 a2 = pack_bf8(wo + (jt * 16 + lr) * 128 + h * 32 + lk * 8);
  bf16x8 b2;
#pragma unroll
  for (int j = 0; j < 8; ++j)
    b2[j] = (short)f2bf(wv[(h * 32 + lk * 8 + j) * 128 + it * 16 + lr]);
  f32x4 c2 = (f32x4){0.f, 0.f, 0.f, 0.f};
  c2 = __builtin_amdgcn_mfma_f32_16x16x32_bf16(a2, b2, c2, 0, 0, 0);
#pragma unroll
  for (int r = 0; r < 4; ++r)
    WB[(size_t)(jt * 16 + lk * 4 + r) * 512 + h * 128 + it * 16 + lr] = f2bf(c2[r]);
}

// WQ[n][h*128+i] = sum_j hV[n][j] * M_h[j][i]; one h per blockIdx.y.
__global__ __launch_bounds__(256) void gemm_wq(
    const float* __restrict__ X, const unsigned short* __restrict__ MT,
    unsigned short* __restrict__ WQb, int M) {
  __shared__ unsigned short Wl[128 * 136];
  const unsigned short* Wsrc = MT + (size_t)blockIdx.y * 16384;
  for (int idx = threadIdx.x; idx < 16384; idx += 256)
    Wl[(idx >> 7) * 136 + (idx & 127)] = Wsrc[idx];
  __syncthreads();

  const int wave = threadIdx.x >> 6, lane = threadIdx.x & 63;
  const int lr = lane & 15, lk = lane >> 4;
  const int row0 = blockIdx.x * 64 + wave * 16;
  const int arow = row0 + lr;

  bf16x8 af[4];
  if (arow < M) {
    const float* xr = X + (size_t)arow * 128;
#pragma unroll
    for (int kk = 0; kk < 4; ++kk) af[kk] = pack_bf8(xr + kk * 32 + lk * 8);
  } else {
#pragma unroll
    for (int kk = 0; kk < 4; ++kk) af[kk] = (bf16x8)(short)0;
  }

  f32x4 acc[8];
#pragma unroll
  for (int ct = 0; ct < 8; ++ct) acc[ct] = (f32x4){0.f, 0.f, 0.f, 0.f};
#pragma unroll
  for (int kk = 0; kk < 4; ++kk)
#pragma unroll
    for (int ct = 0; ct < 8; ++ct) {
      bf16x8 b = *(const bf16x8*)&Wl[(ct * 16 + lr) * 136 + kk * 32 + lk * 8];
      acc[ct] = __builtin_amdgcn_mfma_f32_16x16x32_bf16(af[kk], b, acc[ct], 0, 0, 0);
    }

#pragma unroll
  for (int ct = 0; ct < 8; ++ct)
#pragma unroll
    for (int r = 0; r < 4; ++r) {
      int row = row0 + lk * 4 + r;
      if (row < M)
        WQb[(size_t)row * 512 + blockIdx.y * 128 + ct * 16 + lr] = f2bf(acc[ct][r]);
    }
}

// Fused: logits -> softmax -> aE[n][h][i] = sum_k att[h][k] E[k][i].
// 4 waves/block, one node per wave. No weights touched.
__global__ __launch_bounds__(256, 4) void neigh_aE(
    const float* __restrict__ hE, const int* __restrict__ mask,
    const unsigned short* __restrict__ WQb, unsigned short* __restrict__ aEb,
    int N) {
  __shared__ unsigned short Elds[4][32 * 136];  // E tile bf16 [k][i]
  __shared__ unsigned short attL[4][4 * 32];    // att bf16 [h][k]

  const int wave = threadIdx.x >> 6, lane = threadIdx.x & 63;
  const int lr = lane & 15, lk = lane >> 4;
  const int n = blockIdx.x * 4 + wave;
  if (n >= N) return;
  unsigned short* El = Elds[wave];
  unsigned short* at = attL[wave];
  const float* E = hE + (size_t)n * 4096;

  // load E tile -> bf16 A-fragments + LDS copy
  bf16x8 af[2][4];
#pragma unroll
  for (int rt = 0; rt < 2; ++rt)
#pragma unroll
    for (int kk = 0; kk < 4; ++kk) {
      af[rt][kk] = pack_bf8(E + (rt * 16 + lr) * 128 + kk * 32 + lk * 8);
      *(bf16x8*)&El[(rt * 16 + lr) * 136 + kk * 32 + lk * 8] = af[rt][kk];
    }

  // WQ row as B-operand (rows lr>=4 duplicate head lr&3; cols 4..15 of D junk)
  bf16x8 bq[4];
#pragma unroll
  for (int kk = 0; kk < 4; ++kk)
    bq[kk] = *(const bf16x8*)(WQb + (size_t)n * 512 + (lr & 3) * 128 + kk * 32 + lk * 8);

  // logits D[k][h]: lane holds k = rt*16 + lk*4 + r, h = lr
  f32x4 c0 = (f32x4){0.f, 0.f, 0.f, 0.f};
  f32x4 c1 = (f32x4){0.f, 0.f, 0.f, 0.f};
#pragma unroll
  for (int kk = 0; kk < 4; ++kk) {
    c0 = __builtin_amdgcn_mfma_f32_16x16x32_bf16(af[0][kk], bq[kk], c0, 0, 0, 0);
    c1 = __builtin_amdgcn_mfma_f32_16x16x32_bf16(af[1][kk], bq[kk], c1, 0, 0, 0);
  }

  // masked softmax over k (reduce over lk,regs: 2 shuffles)
  const int4 m0 = *(const int4*)(mask + (size_t)n * 32 + lk * 4);
  const int4 m1 = *(const int4*)(mask + (size_t)n * 32 + 16 + lk * 4);
  float l[2][4];
  l[0][0] = m0.x ? c0[0] * SCALE : NEG_INF;
  l[0][1] = m0.y ? c0[1] * SCALE : NEG_INF;
  l[0][2] = m0.z ? c0[2] * SCALE : NEG_INF;
  l[0][3] = m0.w ? c0[3] * SCALE : NEG_INF;
  l[1][0] = m1.x ? c1[0] * SCALE : NEG_INF;
  l[1][1] = m1.y ? c1[1] * SCALE : NEG_INF;
  l[1][2] = m1.z ? c1[2] * SCALE : NEG_INF;
  l[1][3] = m1.w ? c1[3] * SCALE : NEG_INF;

  float mx = l[0][0];
#pragma unroll
  for (int rt = 0; rt < 2; ++rt)
#pragma unroll
    for (int r = 0; r < 4; ++r) mx = fmaxf(mx, l[rt][r]);
  mx = fmaxf(mx, __shfl_xor(mx, 16, 64));
  mx = fmaxf(mx, __shfl_xor(mx, 32, 64));

  float e[2][4];
  float sum = 0.f;
#pragma unroll
  for (int rt = 0; rt < 2; ++rt)
#pragma unroll
    for (int r = 0; r < 4; ++r) { e[rt][r] = __expf(l[rt][r] - mx); sum += e[rt][r]; }
  sum += __shfl_xor(sum, 16, 64);
  sum += __shfl_xor(sum, 32, 64);
  const float inv = 1.0f / sum;

  if (lr < 4) {  // att[h=lr][k], bf16, packed 4-k at a time
    u16x4 p0, p1;
    p0[0] = f2bf(m0.x ? e[0][0] * inv : 0.f);
    p0[1] = f2bf(m0.y ? e[0][1] * inv : 0.f);
    p0[2] = f2bf(m0.z ? e[0][2] * inv : 0.f);
    p0[3] = f2bf(m0.w ? e[0][3] * inv : 0.f);
    p1[0] = f2bf(m1.x ? e[1][0] * inv : 0.f);
    p1[1] = f2bf(m1.y ? e[1][1] * inv : 0.f);
    p1[2] = f2bf(m1.z ? e[1][2] * inv : 0.f);
    p1[3] = f2bf(m1.w ? e[1][3] * inv : 0.f);
    *(u16x4*)&at[lr * 32 + lk * 4] = p0;
    *(u16x4*)&at[lr * 32 + 16 + lk * 4] = p1;
  }

  // aE: D[m][n] = sum_k att[m&3][k] E[k][ct*16+n];  A broadcast from attL
  bf16x8 aA = *(const bf16x8*)&at[(lr & 3) * 32 + lk * 8];
#pragma unroll
  for (int ct = 0; ct < 8; ++ct) {
    bf16x8 bE;
#pragma unroll
    for (int j = 0; j < 8; ++j)
      bE[j] = (short)El[(lk * 8 + j) * 136 + ct * 16 + lr];
    f32x4 acc = (f32x4){0.f, 0.f, 0.f, 0.f};
    acc = __builtin_amdgcn_mfma_f32_16x16x32_bf16(aA, bE, acc, 0, 0, 0);
    // rows m = lk*4+r hold head h = r (duplicated across lk); lane stores h = lk
    float v = (lk == 0) ? acc[0] : (lk == 1) ? acc[1] : (lk == 2) ? acc[2] : acc[3];
    aEb[(size_t)n * 512 + lk * 128 + ct * 16 + lr] = f2bf(v);
  }
}

// out[n][o] = sum_{h,i} aE[n][h*128+i] * WB[o][h*128+i]
__global__ __launch_bounds__(256) void gemm_out(
    const unsigned short* __restrict__ aEb, const unsigned short* __restrict__ WB,
    float* __restrict__ Y, int M) {
  __shared__ unsigned short Wl[128 * 136];
  const int wave = threadIdx.x >> 6, lane = threadIdx.x & 63;
  const int lr = lane & 15, lk = lane >> 4;
  const int row0 = blockIdx.x * 64 + wave * 16;
  const int arow = row0 + lr;

  f32x4 acc[8];
#pragma unroll
  for (int ct = 0; ct < 8; ++ct) acc[ct] = (f32x4){0.f, 0.f, 0.f, 0.f};

  for (int h = 0; h < 4; ++h) {
    __syncthreads();
    for (int idx = threadIdx.x; idx < 16384; idx += 256)
      Wl[(idx >> 7) * 136 + (idx & 127)] = WB[(size_t)(idx >> 7) * 512 + h * 128 + (idx & 127)];
    __syncthreads();

    bf16x8 af[4];
    if (arow < M) {
#pragma unroll
      for (int kk = 0; kk < 4; ++kk)
        af[kk] = *(const bf16x8*)(aEb + (size_t)arow * 512 + h * 128 + kk * 32 + lk * 8);
    } else {
#pragma unroll
      for (int kk = 0; kk < 4; ++kk) af[kk] = (bf16x8)(short)0;
    }
#pragma unroll
    for (int kk = 0; kk < 4; ++kk)
#pragma unroll
      for (int ct = 0; ct < 8; ++ct) {
        bf16x8 b = *(const bf16x8*)&Wl[(ct * 16 + lr) * 136 + kk * 32 + lk * 8];
        acc[ct] = __builtin_amdgcn_mfma_f32_16x16x32_bf16(af[kk], b, acc[ct], 0, 0, 0);
      }
  }

#pragma unroll
  for (int ct = 0; ct < 8; ++ct)
#pragma unroll
    for (int r = 0; r < 4; ++r) {
      int row = row0 + lk * 4 + r;
      if (row < M) Y[(size_t)row * 128 + ct * 16 + lr] = acc[ct][r];
    }
}

extern "C" void kernel_launch(void* const* d_in, const int* in_sizes, int n_in,
                              void* d_out, int out_size, void* d_ws, size_t ws_size,
                              hipStream_t stream) {
  const float* hV = (const float*)d_in[0];
  const float* hE = (const float*)d_in[1];
  const int* mask = (const int*)d_in[2];
  const float* Wq = (const float*)d_in[3];
  const float* Wk = (const float*)d_in[4];
  const float* Wv = (const float*)d_in[5];
  const float* Wo = (const float*)d_in[6];
  float* out = (float*)d_out;
  const int N = in_sizes[0] / 128;  // 30000

  char* ws = (char*)d_ws;
  unsigned short* MT = (unsigned short*)(ws);            // 4*128*128*2 = 128 KB
  unsigned short* WB = (unsigned short*)(ws + 131072);   // 128*512*2  = 128 KB
  unsigned short* WQb = (unsigned short*)(ws + 262144);               // N*512 bf16
  unsigned short* aEb = (unsigned short*)(ws + 262144 + (size_t)N * 1024);

  fuse_weights<<<64, 256, 0, stream>>>(Wq, Wk, Wv, Wo, MT, WB);
  gemm_wq<<<dim3((N + 63) / 64, 4), 256, 0, stream>>>(hV, MT, WQb, N);
  neigh_aE<<<(N + 3) / 4, 256, 0, stream>>>(hE, mask, WQb, aEb, N);
  gemm_out<<<(N + 63) / 64, 256, 0, stream>>>(aEb, WB, out, N);
}